// Round 2
// baseline (625.305 us; speedup 1.0000x reference)
//
#include <hip/hip_runtime.h>
#include <hip/hip_bf16.h>

#define NT   8192
#define DD   2048
#define HH   1408
#define NE   8
#define CAPT 1024

typedef __bf16 bf16x8 __attribute__((ext_vector_type(8)));
typedef float  f32x4  __attribute__((ext_vector_type(4)));
typedef unsigned short us8 __attribute__((ext_vector_type(8)));

__device__ __forceinline__ unsigned short f2bf(float f) {
  union { float f; unsigned u; } v; v.f = f;
  unsigned r = v.u + 0x7fffu + ((v.u >> 16) & 1u);
  return (unsigned short)(r >> 16);
}

__device__ __forceinline__ void load_lds16(const void* g, void* l) {
  __builtin_amdgcn_global_load_lds(
      (const __attribute__((address_space(1))) unsigned int*)g,
      (__attribute__((address_space(3))) unsigned int*)l, 16, 0, 0);
}

__device__ __forceinline__ void cvt_block(const float* __restrict__ in,
                                          unsigned short* __restrict__ out,
                                          size_t blk, int tid) {
  size_t i = (blk * 256 + tid) * 8;
  const float4* p = reinterpret_cast<const float4*>(in + i);
  float4 a = p[0], b = p[1];
  us8 o;
  o[0] = f2bf(a.x); o[1] = f2bf(a.y); o[2] = f2bf(a.z); o[3] = f2bf(a.w);
  o[4] = f2bf(b.x); o[5] = f2bf(b.y); o[6] = f2bf(b.z); o[7] = f2bf(b.w);
  *reinterpret_cast<us8*>(out + i) = o;
}

// single-tensor fp32->bf16 convert (used for w2 after gateup frees its space)
__global__ __launch_bounds__(256) void cvt_bf16_kernel(
    const float* __restrict__ in, unsigned short* __restrict__ out) {
  cvt_block(in, out, blockIdx.x, threadIdx.x);
}

// merged convert for x, w1, w3 in one dispatch (block ranges select tensor)
__global__ __launch_bounds__(256) void cvt3_bf16_kernel(
    const float* __restrict__ a, unsigned short* __restrict__ ao, int na,
    const float* __restrict__ b, unsigned short* __restrict__ bo, int nb,
    const float* __restrict__ c, unsigned short* __restrict__ co) {
  int blk = blockIdx.x;
  if (blk < na)            cvt_block(a, ao, blk, threadIdx.x);
  else if (blk < na + nb)  cvt_block(b, bo, blk - na, threadIdx.x);
  else                     cvt_block(c, co, blk - na - nb, threadIdx.x);
}

// Fused gate+up GEMM: h = silu(x@w1^T) * (x@w3^T), per-expert.
// Block: 256 thr (4 waves, 2x2), tile 128(M) x 128(N), BK=32.
// Per wave per K-iter: 32 MFMA (~154 cyc) vs 12 ds_read_b128 (~144 cyc).
__global__ __launch_bounds__(256) void gateup_gemm(
    const unsigned short* __restrict__ xb,   // [NT, DD] bf16
    const unsigned short* __restrict__ w1b,  // [NE, HH, DD] bf16
    const unsigned short* __restrict__ w3b,  // [NE, HH, DD] bf16
    const int* __restrict__ counts,
    unsigned short* __restrict__ h)          // [NT, HH] bf16
{
  __shared__ __align__(16) unsigned short As[128 * 32];
  __shared__ __align__(16) unsigned short B1s[128 * 32];
  __shared__ __align__(16) unsigned short B3s[128 * 32];

  const int e  = blockIdx.z;
  const int m0 = blockIdx.y * 128;
  const int n0 = blockIdx.x * 128;

  int start = 0;
  for (int i = 0; i < e; ++i) start += counts[i];

  const int tid  = threadIdx.x;
  const int lane = tid & 63;
  const int wid  = tid >> 6;
  const int lrow = lane >> 2;        // 0..15 within a 16-row chunk
  const int lcol = (lane & 3) * 8;   // 0,8,16,24 (bf16 elems; 16B granules)

  // each wave stages 32 rows (2 chunks) of each of A, B1, B3
  const unsigned short* ga  = xb  + (size_t)(start + m0 + wid * 32 + lrow) * DD + lcol;
  const unsigned short* gb1 = w1b + ((size_t)e * HH + n0 + wid * 32 + lrow) * DD + lcol;
  const unsigned short* gb3 = w3b + ((size_t)e * HH + n0 + wid * 32 + lrow) * DD + lcol;

  unsigned short* lA0 = &As [(wid * 32) * 32      + lane * 8];
  unsigned short* lA1 = &As [(wid * 32 + 16) * 32 + lane * 8];
  unsigned short* lB10 = &B1s[(wid * 32) * 32      + lane * 8];
  unsigned short* lB11 = &B1s[(wid * 32 + 16) * 32 + lane * 8];
  unsigned short* lB30 = &B3s[(wid * 32) * 32      + lane * 8];
  unsigned short* lB31 = &B3s[(wid * 32 + 16) * 32 + lane * 8];

  const int fm  = lane & 15;
  const int fko = (lane >> 4) * 8;
  const int wm  = (wid >> 1) * 64;   // wave M offset
  const int wn  = (wid & 1) * 64;    // wave N offset

  f32x4 acc[2][4][4] = {};

  for (int k0 = 0; k0 < DD; k0 += 32) {
    load_lds16(ga,           lA0);
    load_lds16(ga + 16 * DD, lA1);
    load_lds16(gb1,          lB10);
    load_lds16(gb1 + 16 * DD, lB11);
    load_lds16(gb3,          lB30);
    load_lds16(gb3 + 16 * DD, lB31);
    ga += 32; gb1 += 32; gb3 += 32;
    __builtin_amdgcn_s_waitcnt(0x3f70);  // vmcnt(0)
    __syncthreads();

    bf16x8 af[4];
#pragma unroll
    for (int i = 0; i < 4; ++i)
      af[i] = *reinterpret_cast<const bf16x8*>(&As[(wm + i * 16 + fm) * 32 + fko]);
#pragma unroll
    for (int j = 0; j < 4; ++j) {
      bf16x8 b1 = *reinterpret_cast<const bf16x8*>(&B1s[(wn + j * 16 + fm) * 32 + fko]);
      bf16x8 b3 = *reinterpret_cast<const bf16x8*>(&B3s[(wn + j * 16 + fm) * 32 + fko]);
#pragma unroll
      for (int i = 0; i < 4; ++i) {
        acc[0][i][j] = __builtin_amdgcn_mfma_f32_16x16x32_bf16(af[i], b1, acc[0][i][j], 0, 0, 0);
        acc[1][i][j] = __builtin_amdgcn_mfma_f32_16x16x32_bf16(af[i], b3, acc[1][i][j], 0, 0, 0);
      }
    }
    __syncthreads();
  }

  // epilogue: silu(gate)*up -> bf16 h. C/D layout: col=lane&15, row=quad*4+reg
  const int r0 = (lane >> 4) * 4;
#pragma unroll
  for (int i = 0; i < 4; ++i)
#pragma unroll
    for (int j = 0; j < 4; ++j)
#pragma unroll
      for (int r = 0; r < 4; ++r) {
        int row = m0 + wm + i * 16 + r0 + r;
        int col = n0 + wn + j * 16 + fm;
        float gv = acc[0][i][j][r];
        float uv = acc[1][i][j][r];
        float sv = (gv / (1.0f + __expf(-gv))) * uv;
        h[(size_t)(start + row) * HH + col] = f2bf(sv);
      }
}

// Down GEMM: out = h @ w2^T, per-expert. m97 clone: 128x128 tile, BK=32.
__global__ __launch_bounds__(256) void down_gemm(
    const unsigned short* __restrict__ hb,   // [NT, HH] bf16
    const unsigned short* __restrict__ w2b,  // [NE, DD, HH] bf16
    const int* __restrict__ counts,
    float* __restrict__ out)                 // [NT, DD] fp32
{
  __shared__ __align__(16) unsigned short Hs[128 * 32];
  __shared__ __align__(16) unsigned short Ws[128 * 32];

  const int e  = blockIdx.z;
  const int m0 = blockIdx.y * 128;
  const int n0 = blockIdx.x * 128;

  int start = 0;
  for (int i = 0; i < e; ++i) start += counts[i];

  const int tid  = threadIdx.x;
  const int lane = tid & 63;
  const int wid  = tid >> 6;
  const int lrow = lane >> 2;
  const int lcol = (lane & 3) * 8;

  const unsigned short* ga = hb  + (size_t)(start + m0 + wid * 32 + lrow) * HH + lcol;
  const unsigned short* gb = w2b + ((size_t)e * DD + n0 + wid * 32 + lrow) * HH + lcol;

  unsigned short* lH0 = &Hs[(wid * 32) * 32      + lane * 8];
  unsigned short* lH1 = &Hs[(wid * 32 + 16) * 32 + lane * 8];
  unsigned short* lW0 = &Ws[(wid * 32) * 32      + lane * 8];
  unsigned short* lW1 = &Ws[(wid * 32 + 16) * 32 + lane * 8];

  const int fm  = lane & 15;
  const int fko = (lane >> 4) * 8;
  const int wm  = (wid >> 1) * 64;
  const int wn  = (wid & 1) * 64;

  f32x4 acc[4][4] = {};

  for (int k0 = 0; k0 < HH; k0 += 32) {
    load_lds16(ga,           lH0);
    load_lds16(ga + 16 * HH, lH1);
    load_lds16(gb,           lW0);
    load_lds16(gb + 16 * HH, lW1);
    ga += 32; gb += 32;
    __builtin_amdgcn_s_waitcnt(0x3f70);  // vmcnt(0)
    __syncthreads();

    bf16x8 af[4];
#pragma unroll
    for (int i = 0; i < 4; ++i)
      af[i] = *reinterpret_cast<const bf16x8*>(&Hs[(wm + i * 16 + fm) * 32 + fko]);
#pragma unroll
    for (int j = 0; j < 4; ++j) {
      bf16x8 bf_ = *reinterpret_cast<const bf16x8*>(&Ws[(wn + j * 16 + fm) * 32 + fko]);
#pragma unroll
      for (int i = 0; i < 4; ++i)
        acc[i][j] = __builtin_amdgcn_mfma_f32_16x16x32_bf16(af[i], bf_, acc[i][j], 0, 0, 0);
    }
    __syncthreads();
  }

  const int r0 = (lane >> 4) * 4;
#pragma unroll
  for (int i = 0; i < 4; ++i)
#pragma unroll
    for (int j = 0; j < 4; ++j)
#pragma unroll
      for (int r = 0; r < 4; ++r) {
        int row = m0 + wm + i * 16 + r0 + r;
        int col = n0 + wn + j * 16 + fm;
        out[(size_t)(start + row) * DD + col] = acc[i][j][r];
      }
}

extern "C" void kernel_launch(void* const* d_in, const int* in_sizes, int n_in,
                              void* d_out, int out_size, void* d_ws, size_t ws_size,
                              hipStream_t stream) {
  // setup_inputs order: x, num_tokens_per_expert, w1, w2, w3
  const float* x  = (const float*)d_in[0];
  const int*   cn = (const int*)d_in[1];
  const float* w1 = (const float*)d_in[2];
  const float* w2 = (const float*)d_in[3];
  const float* w3 = (const float*)d_in[4];
  float* out = (float*)d_out;

  // workspace layout (bytes):
  //   [0,            33554432)  xb   (later aliased by w2b)
  //   [33554432,     79691776)  w1b  (later aliased by w2b tail)
  //   [79691776,    125829120)  w3b
  //   [125829120,   148897792)  h
  char* ws = (char*)d_ws;
  unsigned short* xb  = (unsigned short*)(ws + 0);
  unsigned short* w1b = (unsigned short*)(ws + 33554432);
  unsigned short* w3b = (unsigned short*)(ws + 79691776);
  unsigned short* hb  = (unsigned short*)(ws + 125829120);
  unsigned short* w2b = (unsigned short*)(ws + 0);  // safe: xb/w1b dead after gateup_gemm

  const int nx = (NT * DD) / 2048;         // 8192 blocks
  const int nw = (NE * HH * DD) / 2048;    // 11264 blocks
  cvt3_bf16_kernel<<<nx + 2 * nw, 256, 0, stream>>>(x, xb, nx, w1, w1b, nw, w3, w3b);

  dim3 g1(HH / 128, CAPT / 128, NE);       // (11, 8, 8)
  gateup_gemm<<<g1, 256, 0, stream>>>(xb, w1b, w3b, cn, hb);

  cvt_bf16_kernel<<<nw, 256, 0, stream>>>(w2, w2b);

  dim3 g2(DD / 128, CAPT / 128, NE);       // (16, 8, 8)
  down_gemm<<<g2, 256, 0, stream>>>(hb, w2b, cn, out);
}

// Round 3
// 538.980 us; speedup vs baseline: 1.1602x; 1.1602x over previous
//
#include <hip/hip_runtime.h>
#include <hip/hip_bf16.h>

#define NT   8192
#define DD   2048
#define HH   1408
#define NE   8
#define CAPT 1024

typedef __bf16 bf16x8 __attribute__((ext_vector_type(8)));
typedef float  f32x4  __attribute__((ext_vector_type(4)));
typedef unsigned short us8 __attribute__((ext_vector_type(8)));

__device__ __forceinline__ unsigned short f2bf(float f) {
  union { float f; unsigned u; } v; v.f = f;
  unsigned r = v.u + 0x7fffu + ((v.u >> 16) & 1u);
  return (unsigned short)(r >> 16);
}

__device__ __forceinline__ void load_lds16(const void* g, void* l) {
  __builtin_amdgcn_global_load_lds(
      (const __attribute__((address_space(1))) unsigned int*)g,
      (__attribute__((address_space(3))) unsigned int*)l, 16, 0, 0);
}

// raw barrier/waitcnt: avoid __syncthreads' implicit s_waitcnt vmcnt(0) drain
__device__ __forceinline__ void wait_vm4() { asm volatile("s_waitcnt vmcnt(4)" ::: "memory"); }
__device__ __forceinline__ void wait_vm0() { asm volatile("s_waitcnt vmcnt(0)" ::: "memory"); }
__device__ __forceinline__ void barrier()  { asm volatile("s_barrier" ::: "memory"); }

__device__ __forceinline__ void cvt_block(const float* __restrict__ in,
                                          unsigned short* __restrict__ out,
                                          size_t blk, int tid) {
  size_t i = (blk * 256 + tid) * 8;
  const float4* p = reinterpret_cast<const float4*>(in + i);
  float4 a = p[0], b = p[1];
  us8 o;
  o[0] = f2bf(a.x); o[1] = f2bf(a.y); o[2] = f2bf(a.z); o[3] = f2bf(a.w);
  o[4] = f2bf(b.x); o[5] = f2bf(b.y); o[6] = f2bf(b.z); o[7] = f2bf(b.w);
  *reinterpret_cast<us8*>(out + i) = o;
}

__global__ __launch_bounds__(256) void cvt_bf16_kernel(
    const float* __restrict__ in, unsigned short* __restrict__ out) {
  cvt_block(in, out, blockIdx.x, threadIdx.x);
}

__global__ __launch_bounds__(256) void cvt3_bf16_kernel(
    const float* __restrict__ a, unsigned short* __restrict__ ao, int na,
    const float* __restrict__ b, unsigned short* __restrict__ bo, int nb,
    const float* __restrict__ c, unsigned short* __restrict__ co) {
  int blk = blockIdx.x;
  if (blk < na)            cvt_block(a, ao, blk, threadIdx.x);
  else if (blk < na + nb)  cvt_block(b, bo, blk - na, threadIdx.x);
  else                     cvt_block(c, co, blk - na - nb, threadIdx.x);
}

// Fused gate+up GEMM: h = silu(x@w1^T) * (x@w3^T), per-expert.
// Tile 128(M) x 64(N), BK=32, 4 waves (2x2, wave tile 64x32 per gate).
// Double-buffered LDS; prefetch tile k+1 before waiting on tile k
// (s_waitcnt vmcnt(4), never 0 — latency hidden by one full compute phase).
__global__ __launch_bounds__(256) void gateup_gemm(
    const unsigned short* __restrict__ xb,   // [NT, DD] bf16
    const unsigned short* __restrict__ w1b,  // [NE, HH, DD] bf16
    const unsigned short* __restrict__ w3b,  // [NE, HH, DD] bf16
    const int* __restrict__ counts,
    unsigned short* __restrict__ h)          // [NT, HH] bf16
{
  __shared__ __align__(16) unsigned short As [2][128 * 32];
  __shared__ __align__(16) unsigned short B1s[2][64 * 32];
  __shared__ __align__(16) unsigned short B3s[2][64 * 32];

  const int e  = blockIdx.z;
  const int m0 = blockIdx.y * 128;
  const int n0 = blockIdx.x * 64;

  int start = 0;
  for (int i = 0; i < e; ++i) start += counts[i];

  const int tid  = threadIdx.x;
  const int lane = tid & 63;
  const int wid  = tid >> 6;
  const int lrow = lane >> 2;        // 0..15 within a 16-row chunk
  const int lcol = (lane & 3) * 8;   // 0,8,16,24 (bf16 elems; 16B granules)

  const unsigned short* ga  = xb  + (size_t)(start + m0 + wid * 32 + lrow) * DD + lcol;
  const unsigned short* gb1 = w1b + ((size_t)e * HH + n0 + wid * 16 + lrow) * DD + lcol;
  const unsigned short* gb3 = w3b + ((size_t)e * HH + n0 + wid * 16 + lrow) * DD + lcol;

  const int aoff0 = (wid * 32) * 32      + lane * 8;
  const int aoff1 = (wid * 32 + 16) * 32 + lane * 8;
  const int boff  = (wid * 16) * 32      + lane * 8;

  const int fm  = lane & 15;
  const int fko = (lane >> 4) * 8;
  const int wm  = (wid >> 1) * 64;   // wave M offset
  const int wn  = (wid & 1) * 32;    // wave N offset

  // prologue: stage tile 0 into buffer 0
  load_lds16(ga,           &As [0][aoff0]);
  load_lds16(ga + 16 * DD, &As [0][aoff1]);
  load_lds16(gb1,          &B1s[0][boff]);
  load_lds16(gb3,          &B3s[0][boff]);
  ga += 32; gb1 += 32; gb3 += 32;

  f32x4 acc[2][4][2] = {};
  const int iters = DD / 32;  // 64

  for (int it = 0; it < iters; ++it) {
    const int cur = it & 1;
    const int nxt = cur ^ 1;
    if (it < iters - 1) {
      load_lds16(ga,           &As [nxt][aoff0]);
      load_lds16(ga + 16 * DD, &As [nxt][aoff1]);
      load_lds16(gb1,          &B1s[nxt][boff]);
      load_lds16(gb3,          &B3s[nxt][boff]);
      ga += 32; gb1 += 32; gb3 += 32;
      wait_vm4();            // only tile-it's 4 loads must be done
    } else {
      wait_vm0();
    }
    barrier();               // all waves' tile-it stages visible

    bf16x8 af[4];
#pragma unroll
    for (int i = 0; i < 4; ++i)
      af[i] = *reinterpret_cast<const bf16x8*>(&As[cur][(wm + i * 16 + fm) * 32 + fko]);
#pragma unroll
    for (int j = 0; j < 2; ++j) {
      bf16x8 b1 = *reinterpret_cast<const bf16x8*>(&B1s[cur][(wn + j * 16 + fm) * 32 + fko]);
      bf16x8 b3 = *reinterpret_cast<const bf16x8*>(&B3s[cur][(wn + j * 16 + fm) * 32 + fko]);
#pragma unroll
      for (int i = 0; i < 4; ++i) {
        acc[0][i][j] = __builtin_amdgcn_mfma_f32_16x16x32_bf16(af[i], b1, acc[0][i][j], 0, 0, 0);
        acc[1][i][j] = __builtin_amdgcn_mfma_f32_16x16x32_bf16(af[i], b3, acc[1][i][j], 0, 0, 0);
      }
    }
    barrier();               // all reads of buf[cur] done before it's re-staged
  }

  // epilogue: silu(gate)*up -> bf16 h. C/D layout: col=lane&15, row=quad*4+reg
  const int r0 = (lane >> 4) * 4;
#pragma unroll
  for (int i = 0; i < 4; ++i)
#pragma unroll
    for (int j = 0; j < 2; ++j)
#pragma unroll
      for (int r = 0; r < 4; ++r) {
        int row = m0 + wm + i * 16 + r0 + r;
        int col = n0 + wn + j * 16 + fm;
        float gv = acc[0][i][j][r];
        float uv = acc[1][i][j][r];
        float sv = (gv / (1.0f + __expf(-gv))) * uv;
        h[(size_t)(start + row) * HH + col] = f2bf(sv);
      }
}

// Down GEMM: out = h @ w2^T, per-expert. 128x128 tile, BK=32, double-buffered.
__global__ __launch_bounds__(256) void down_gemm(
    const unsigned short* __restrict__ hb,   // [NT, HH] bf16
    const unsigned short* __restrict__ w2b,  // [NE, DD, HH] bf16
    const int* __restrict__ counts,
    float* __restrict__ out)                 // [NT, DD] fp32
{
  __shared__ __align__(16) unsigned short Hs[2][128 * 32];
  __shared__ __align__(16) unsigned short Ws[2][128 * 32];

  const int e  = blockIdx.z;
  const int m0 = blockIdx.y * 128;
  const int n0 = blockIdx.x * 128;

  int start = 0;
  for (int i = 0; i < e; ++i) start += counts[i];

  const int tid  = threadIdx.x;
  const int lane = tid & 63;
  const int wid  = tid >> 6;
  const int lrow = lane >> 2;
  const int lcol = (lane & 3) * 8;

  const unsigned short* ga = hb  + (size_t)(start + m0 + wid * 32 + lrow) * HH + lcol;
  const unsigned short* gb = w2b + ((size_t)e * DD + n0 + wid * 32 + lrow) * HH + lcol;

  const int off0 = (wid * 32) * 32      + lane * 8;
  const int off1 = (wid * 32 + 16) * 32 + lane * 8;

  const int fm  = lane & 15;
  const int fko = (lane >> 4) * 8;
  const int wm  = (wid >> 1) * 64;
  const int wn  = (wid & 1) * 64;

  load_lds16(ga,           &Hs[0][off0]);
  load_lds16(ga + 16 * HH, &Hs[0][off1]);
  load_lds16(gb,           &Ws[0][off0]);
  load_lds16(gb + 16 * HH, &Ws[0][off1]);
  ga += 32; gb += 32;

  f32x4 acc[4][4] = {};
  const int iters = HH / 32;  // 44

  for (int it = 0; it < iters; ++it) {
    const int cur = it & 1;
    const int nxt = cur ^ 1;
    if (it < iters - 1) {
      load_lds16(ga,           &Hs[nxt][off0]);
      load_lds16(ga + 16 * HH, &Hs[nxt][off1]);
      load_lds16(gb,           &Ws[nxt][off0]);
      load_lds16(gb + 16 * HH, &Ws[nxt][off1]);
      ga += 32; gb += 32;
      wait_vm4();
    } else {
      wait_vm0();
    }
    barrier();

    bf16x8 af[4];
#pragma unroll
    for (int i = 0; i < 4; ++i)
      af[i] = *reinterpret_cast<const bf16x8*>(&Hs[cur][(wm + i * 16 + fm) * 32 + fko]);
#pragma unroll
    for (int j = 0; j < 4; ++j) {
      bf16x8 bf_ = *reinterpret_cast<const bf16x8*>(&Ws[cur][(wn + j * 16 + fm) * 32 + fko]);
#pragma unroll
      for (int i = 0; i < 4; ++i)
        acc[i][j] = __builtin_amdgcn_mfma_f32_16x16x32_bf16(af[i], bf_, acc[i][j], 0, 0, 0);
    }
    barrier();
  }

  const int r0 = (lane >> 4) * 4;
#pragma unroll
  for (int i = 0; i < 4; ++i)
#pragma unroll
    for (int j = 0; j < 4; ++j)
#pragma unroll
      for (int r = 0; r < 4; ++r) {
        int row = m0 + wm + i * 16 + r0 + r;
        int col = n0 + wn + j * 16 + fm;
        out[(size_t)(start + row) * DD + col] = acc[i][j][r];
      }
}

extern "C" void kernel_launch(void* const* d_in, const int* in_sizes, int n_in,
                              void* d_out, int out_size, void* d_ws, size_t ws_size,
                              hipStream_t stream) {
  // setup_inputs order: x, num_tokens_per_expert, w1, w2, w3
  const float* x  = (const float*)d_in[0];
  const int*   cn = (const int*)d_in[1];
  const float* w1 = (const float*)d_in[2];
  const float* w2 = (const float*)d_in[3];
  const float* w3 = (const float*)d_in[4];
  float* out = (float*)d_out;

  // workspace layout (bytes):
  //   [0,            33554432)  xb   (later aliased by w2b)
  //   [33554432,     79691776)  w1b  (later aliased by w2b tail)
  //   [79691776,    125829120)  w3b
  //   [125829120,   148897792)  h
  char* ws = (char*)d_ws;
  unsigned short* xb  = (unsigned short*)(ws + 0);
  unsigned short* w1b = (unsigned short*)(ws + 33554432);
  unsigned short* w3b = (unsigned short*)(ws + 79691776);
  unsigned short* hb  = (unsigned short*)(ws + 125829120);
  unsigned short* w2b = (unsigned short*)(ws + 0);  // safe: xb/w1b dead after gateup_gemm

  const int nx = (NT * DD) / 2048;         // 8192 blocks
  const int nw = (NE * HH * DD) / 2048;    // 11264 blocks
  cvt3_bf16_kernel<<<nx + 2 * nw, 256, 0, stream>>>(x, xb, nx, w1, w1b, nw, w3, w3b);

  dim3 g1(HH / 64, CAPT / 128, NE);        // (22, 8, 8) = 1408 blocks
  gateup_gemm<<<g1, 256, 0, stream>>>(xb, w1b, w3b, cn, hb);

  cvt_bf16_kernel<<<nw, 256, 0, stream>>>(w2, w2b);

  dim3 g2(DD / 128, CAPT / 128, NE);       // (16, 8, 8) = 1024 blocks
  down_gemm<<<g2, 256, 0, stream>>>(hb, w2b, cn, out);
}